// Round 17
// baseline (319.707 us; speedup 1.0000x reference)
//
#include <hip/hip_runtime.h>
#include <hip/hip_fp16.h>
#include <math.h>
#include <stddef.h>

#define D_DIM 128
#define NUM_RBF 20
typedef unsigned short ushort_t;
typedef unsigned int uint_t;
typedef _Float16 h2v __attribute__((ext_vector_type(2)));
typedef _Float16 half8_t __attribute__((ext_vector_type(8)));
typedef float float4_t __attribute__((ext_vector_type(4)));
constexpr float PI_F = 3.14159265358979323846f;
constexpr float CUT_OFF_F = 5.0f;
constexpr float SILU_SCALE_F = 1.0f / 0.6f;

__device__ __forceinline__ uint_t pack2h(float a, float b) {
  __half2 h2 = __floats2half2_rn(a, b);
  return *reinterpret_cast<uint_t*>(&h2);
}
__device__ __forceinline__ float h2f(ushort_t u) {
  __half h = __ushort_as_half(u);
  return __half2float(h);
}
__device__ __forceinline__ float h2f_lo(uint_t u) { return h2f((ushort_t)(u & 0xffffu)); }
__device__ __forceinline__ float h2f_hi(uint_t u) { return h2f((ushort_t)(u >> 16)); }
__device__ __forceinline__ h2v u2h2(uint_t u) {
  h2v r;
  __builtin_memcpy(&r, &u, 4);
  return r;
}

#if defined(__has_builtin)
#if __has_builtin(__builtin_amdgcn_fdot2)
#define HAVE_FDOT2 1
#endif
#endif

__device__ __forceinline__ float fdot2f(h2v a, h2v b, float c) {
#ifdef HAVE_FDOT2
  return __builtin_amdgcn_fdot2(a, b, c, false);
#else
  return c + (float)a.x * (float)b.x + (float)a.y * (float)b.y;
#endif
}

// 64B per-edge record: all wave-uniform data in one scalar-loadable block.
struct __align__(16) EdgeRec {
  uint_t rb[10];   // rbf packed fp16x2
  uint_t src;      // source node
  float dx, dy, dz;
  uint_t pad[2];
};

// ---------------------------------------------------------------------------
// MFMA node projection + merged-buffer build + counts zeroing (R13-verified).
// ---------------------------------------------------------------------------
__device__ __forceinline__ void stage_wt(const float* __restrict__ W,
                                         _Float16* __restrict__ Wt, int t,
                                         int f4stride, int f4base) {
  const float4* Wv = reinterpret_cast<const float4*>(W);
#pragma unroll
  for (int i = 0; i < 8; ++i) {
    int pid = t + i * 256;            // 0..2047: 64 k-pairs x 32 n-float4s
    int k = (pid >> 5) * 2;
    int nf = pid & 31;
    float4 a = Wv[(size_t)k * f4stride + f4base + nf];
    float4 b = Wv[(size_t)(k + 1) * f4stride + f4base + nf];
    const float av[4] = {a.x, a.y, a.z, a.w};
    const float bv[4] = {b.x, b.y, b.z, b.w};
    const int n0 = nf * 4;
#pragma unroll
    for (int j = 0; j < 4; ++j)
      *reinterpret_cast<uint_t*>(&Wt[(n0 + j) * 136 + k]) =
          pack2h(av[j], bv[j]);
  }
}

__global__ __launch_bounds__(256) void proj_kernel(
    const float* __restrict__ X, const float* __restrict__ W1,
    const float* __restrict__ b1, const float* __restrict__ W2,
    const float* __restrict__ b2, const float* __restrict__ vf,
    uint_t* __restrict__ merged, int* __restrict__ counts, int N) {
  __shared__ alignas(16) _Float16 smem[26112];  // Xs[64*136] + Wt[128*136]
  _Float16* Xs = smem;
  _Float16* Wt = smem + 8704;

  const int t = threadIdx.x;
  const int w = t >> 6;        // wave 0..3
  const int l = t & 63;        // lane
  const int nb = blockIdx.x * 64;

  // ---- fold-in: zero the CSR counts array ----
  {
    int z = blockIdx.x * 256 + t;
    if (z < N) counts[z] = 0;
  }

  // ---- stage X tile: [64][128] fp32 -> Xs[64][136] fp16 ----
  {
    const float4* Xv = reinterpret_cast<const float4*>(X);
#pragma unroll
    for (int i = 0; i < 8; ++i) {
      int g = t + i * 256;            // 0..2047
      int row = g >> 5, k0 = (g & 31) * 4;
      int node = nb + row;
      float4 v = (node < N) ? Xv[(size_t)nb * 32 + g]
                            : make_float4(0.f, 0.f, 0.f, 0.f);
      uint_t* dst = reinterpret_cast<uint_t*>(&Xs[row * 136 + k0]);
      dst[0] = pack2h(v.x, v.y);
      dst[1] = pack2h(v.z, v.w);
    }
  }
  stage_wt(W1, Wt, t, 32, 0);
  __syncthreads();

  const int arow = w * 16 + (l & 15);
  const int koff = (l >> 4) * 8;
  const int bcol = l & 15;

  // ---- phase 1: H = X @ W1 ----
  half8_t af[4];
#pragma unroll
  for (int s = 0; s < 4; ++s)
    af[s] = *reinterpret_cast<const half8_t*>(&Xs[arow * 136 + s * 32 + koff]);

  float4_t acc[8];
#pragma unroll
  for (int c = 0; c < 8; ++c) {
    float4_t a = {0.f, 0.f, 0.f, 0.f};
#pragma unroll
    for (int s = 0; s < 4; ++s) {
      half8_t bf = *reinterpret_cast<const half8_t*>(
          &Wt[(c * 16 + bcol) * 136 + s * 32 + koff]);
      a = __builtin_amdgcn_mfma_f32_16x16x32_f16(af[s], bf, a, 0, 0, 0);
    }
    acc[c] = a;
  }

  __syncthreads();  // all Xs/Wt reads done before overwrite

  // ---- bias + scaled-silu -> H (fp16) into Xs; stage W2 chunk 0 ----
#pragma unroll
  for (int c = 0; c < 8; ++c) {
    const int col = c * 16 + bcol;
    const float bv = b1[col];
#pragma unroll
    for (int r = 0; r < 4; ++r) {
      const int row = w * 16 + (l >> 4) * 4 + r;
      float hv = acc[c][r] + bv;
      hv = hv * SILU_SCALE_F / (1.0f + expf(-hv));
      Xs[row * 136 + col] = (_Float16)hv;
    }
  }
  stage_wt(W2, Wt, t, 96, 0);
  __syncthreads();

  // ---- phase 2: S = H @ W2 + b2, 3 col-chunks of 128; results in regs ----
  half8_t ha[4];
#pragma unroll
  for (int s = 0; s < 4; ++s)
    ha[s] = *reinterpret_cast<const half8_t*>(&Xs[arow * 136 + s * 32 + koff]);

  uint_t pk[3][8][2];   // packed fp16 results; fully static indexing
#pragma unroll
  for (int cn = 0; cn < 3; ++cn) {
    if (cn > 0) {
      __syncthreads();                // prev chunk's Wt reads done
      stage_wt(W2, Wt, t, 96, cn * 32);
      __syncthreads();
    }
#pragma unroll
    for (int c = 0; c < 8; ++c) {
      float4_t a = {0.f, 0.f, 0.f, 0.f};
#pragma unroll
      for (int s = 0; s < 4; ++s) {
        half8_t bf = *reinterpret_cast<const half8_t*>(
            &Wt[(c * 16 + bcol) * 136 + s * 32 + koff]);
        a = __builtin_amdgcn_mfma_f32_16x16x32_f16(ha[s], bf, a, 0, 0, 0);
      }
      const float bv = b2[cn * 128 + c * 16 + bcol];
      pk[cn][c][0] = pack2h(a[0] + bv, a[1] + bv);
      pk[cn][c][1] = pack2h(a[2] + bv, a[3] + bv);
    }
  }

  // ---- bounce S to LDS natural [64][392] ----
  __syncthreads();                    // all Wt reads done; smem reusable
  ushort_t* sh = reinterpret_cast<ushort_t*>(smem);
  {
    const int rbase = w * 16 + (l >> 4) * 4;
#pragma unroll
    for (int cn = 0; cn < 3; ++cn)
#pragma unroll
      for (int c = 0; c < 8; ++c) {
        const int gcol = cn * 128 + c * 16 + bcol;
        sh[(rbase + 0) * 392 + gcol] = (ushort_t)(pk[cn][c][0] & 0xffffu);
        sh[(rbase + 1) * 392 + gcol] = (ushort_t)(pk[cn][c][0] >> 16);
        sh[(rbase + 2) * 392 + gcol] = (ushort_t)(pk[cn][c][1] & 0xffffu);
        sh[(rbase + 3) * 392 + gcol] = (ushort_t)(pk[cn][c][1] >> 16);
      }
  }
  __syncthreads();

  // ---- merged build, vectorized 4 chans/work-item ----
#pragma unroll
  for (int k = 0; k < 8; ++k) {
    const int P = k * 256 + t;        // 0..2047
    const int ln = P >> 5;            // local node 0..63
    const int cg = (P & 31) * 4;      // chan group base 0,4,..,124
    const int node = nb + ln;
    if (node < N) {
      const ushort_t* sp = &sh[ln * 392 + 3 * cg];
      uint2 sa = *reinterpret_cast<const uint2*>(sp);
      uint2 sb = *reinterpret_cast<const uint2*>(sp + 4);
      uint2 sc = *reinterpret_cast<const uint2*>(sp + 8);
      ushort_t s12[12];
      s12[0] = (ushort_t)(sa.x & 0xffffu);  s12[1] = (ushort_t)(sa.x >> 16);
      s12[2] = (ushort_t)(sa.y & 0xffffu);  s12[3] = (ushort_t)(sa.y >> 16);
      s12[4] = (ushort_t)(sb.x & 0xffffu);  s12[5] = (ushort_t)(sb.x >> 16);
      s12[6] = (ushort_t)(sb.y & 0xffffu);  s12[7] = (ushort_t)(sb.y >> 16);
      s12[8] = (ushort_t)(sc.x & 0xffffu);  s12[9] = (ushort_t)(sc.x >> 16);
      s12[10] = (ushort_t)(sc.y & 0xffffu); s12[11] = (ushort_t)(sc.y >> 16);

      const float4* vp =
          reinterpret_cast<const float4*>(vf + ((size_t)node * 128 + cg) * 3);
      float4 v0 = vp[0], v1 = vp[1], v2 = vp[2];
      float vv[12] = {v0.x, v0.y, v0.z, v0.w, v1.x, v1.y,
                      v1.z, v1.w, v2.x, v2.y, v2.z, v2.w};

      uint_t o[12];
#pragma unroll
      for (int j = 0; j < 4; ++j) {
        o[3 * j + 0] = (uint_t)s12[3 * j] | ((uint_t)s12[3 * j + 1] << 16);
        o[3 * j + 1] =
            (uint_t)s12[3 * j + 2] |
            ((uint_t)__half_as_ushort(__float2half_rn(vv[3 * j])) << 16);
        o[3 * j + 2] = pack2h(vv[3 * j + 1], vv[3 * j + 2]);
      }
      uint_t* mp = merged + ((size_t)node * 128 + cg) * 3;
      *reinterpret_cast<uint4*>(mp) = make_uint4(o[0], o[1], o[2], o[3]);
      *reinterpret_cast<uint4*>(mp + 4) = make_uint4(o[4], o[5], o[6], o[7]);
      *reinterpret_cast<uint4*>(mp + 8) = make_uint4(o[8], o[9], o[10], o[11]);
    }
  }
}

// ---------------------------------------------------------------------------
// CSR build: hist + self-basing scan.
// ---------------------------------------------------------------------------
__global__ void hist_kernel(const int* __restrict__ tgt, int* __restrict__ counts,
                            int E) {
  int e = blockIdx.x * 256 + threadIdx.x;
  if (e < E) atomicAdd(&counts[tgt[e]], 1);
}

__global__ void scan_block_kernel(const int* __restrict__ counts,
                                  int* __restrict__ offsets,
                                  int* __restrict__ cursor, int N, int E) {
  __shared__ int part[256];
  __shared__ int chunk_base_sh;
  int b = blockIdx.x, t = threadIdx.x;

  // ---- chunk base: sum counts[0 .. b*1024) (int4 reads, block reduce) ----
  {
    int s = 0;
    const int4* c4 = reinterpret_cast<const int4*>(counts);
    const int lim4 = b * 256;              // b*1024/4
    for (int j = t; j < lim4; j += 256) {
      int4 v = c4[j];
      s += v.x + v.y + v.z + v.w;
    }
    part[t] = s;
    __syncthreads();
    for (int off = 128; off > 0; off >>= 1) {
      if (t < off) part[t] += part[t + off];
      __syncthreads();
    }
    if (t == 0) chunk_base_sh = part[0];
    __syncthreads();
  }

  int base = b * 1024 + t * 4;
  int v[4];
#pragma unroll
  for (int j = 0; j < 4; ++j) v[j] = (base + j < N) ? counts[base + j] : 0;
  int local = v[0] + v[1] + v[2] + v[3];
  part[t] = local;
  __syncthreads();
  for (int off = 1; off < 256; off <<= 1) {
    int x = 0;
    if (t >= off) x = part[t - off];
    __syncthreads();
    if (t >= off) part[t] += x;
    __syncthreads();
  }
  int run = chunk_base_sh + (part[t] - local);
#pragma unroll
  for (int j = 0; j < 4; ++j) {
    if (base + j < N) {
      offsets[base + j] = run;
      cursor[base + j] = run;
      run += v[j];
    }
  }
  if (b == 0 && t == 0) offsets[N] = E;
}

// ---------------------------------------------------------------------------
// Fused edge geometry + CSR scatter into 64B EdgeRec records.
// ---------------------------------------------------------------------------
__global__ void edge_geom_kernel(const float* __restrict__ pos,
                                 const int* __restrict__ src,
                                 const int* __restrict__ tgt,
                                 int* __restrict__ cursor,
                                 EdgeRec* __restrict__ recs, int E) {
  int e = blockIdx.x * 256 + threadIdx.x;
  if (e >= E) return;
  const int sn = src[e];
  const int tn = tgt[e];
  const float rx = pos[tn * 3 + 0] - pos[sn * 3 + 0];
  const float ry = pos[tn * 3 + 1] - pos[sn * 3 + 1];
  const float rz = pos[tn * 3 + 2] - pos[sn * 3 + 2];
  const float dist = sqrtf(rx * rx + ry * ry + rz * rz);
  const float inv = 1.0f / dist;

  const float ang = dist * (PI_F / CUT_OFF_F);
  float s1, c1;
  sincosf(ang, &s1, &c1);
  float sk = s1, ck = c1;
  float rb[NUM_RBF];
  rb[0] = s1 * inv;
#pragma unroll
  for (int r = 1; r < NUM_RBF; ++r) {
    float sn2 = sk * c1 + ck * s1;
    ck = ck * c1 - sk * s1;
    sk = sn2;
    rb[r] = sk * inv;
  }

  const int p = atomicAdd(&cursor[tn], 1);
  uint_t us[10];
#pragma unroll
  for (int q = 0; q < 10; ++q) us[q] = pack2h(rb[2 * q], rb[2 * q + 1]);
  uint_t* o = reinterpret_cast<uint_t*>(&recs[p]);
  *reinterpret_cast<uint4*>(o) = make_uint4(us[0], us[1], us[2], us[3]);
  *reinterpret_cast<uint4*>(o + 4) = make_uint4(us[4], us[5], us[6], us[7]);
  *reinterpret_cast<uint4*>(o + 8) =
      make_uint4(us[8], us[9], (uint_t)sn, __float_as_uint(rx * inv));
  *reinterpret_cast<uint4*>(o + 12) =
      make_uint4(__float_as_uint(ry * inv), __float_as_uint(rz * inv), 0u, 0u);
}

// ---------------------------------------------------------------------------
// Node gather. One wave-uniform 64B record + 3 per-lane merged dwords per
// edge. x4 unroll with upfront loads; v_cos cutoff. NPB=16 (halves the
// 63-load Wr preamble share vs NPB=8; 3125 blocks x 2 waves still ~24
// waves/CU of work — fully resident).
// ---------------------------------------------------------------------------
#define NODES_PER_BLOCK 16

__device__ __forceinline__ float cutoff_f(float x) {
#if defined(__has_builtin)
#if __has_builtin(__builtin_amdgcn_cosf)
  float c = __builtin_amdgcn_cosf(x * 0.1f);   // v_cos_f32: revolutions
#else
  float c = __cosf(x * (PI_F / CUT_OFF_F));
#endif
#else
  float c = __cosf(x * (PI_F / CUT_OFF_F));
#endif
  return (x < CUT_OFF_F) ? 0.5f + 0.5f * c : 0.f;
}

__device__ __forceinline__ void edge_body(const EdgeRec& e, uint_t su0,
                                          uint_t su1, uint_t su2,
                                          const h2v* wr0h, const h2v* wr1h,
                                          const h2v* wr2h, float br0, float br1,
                                          float br2, float& accs, float& av0,
                                          float& av1, float& av2) {
  float f0 = br0, f1 = br1, f2 = br2;
#pragma unroll
  for (int q = 0; q < 10; ++q) {
    h2v r = u2h2(e.rb[q]);
    f0 = fdot2f(r, wr0h[q], f0);
    f1 = fdot2f(r, wr1h[q], f1);
    f2 = fdot2f(r, wr2h[q], f2);
  }
  f0 = cutoff_f(f0);
  f1 = cutoff_f(f1);
  f2 = cutoff_f(f2);
  const float m0 = h2f_lo(su0) * f0;
  const float m1 = h2f_hi(su0) * f1;
  const float m2 = h2f_lo(su1) * f2;
  accs += m0;
  av0 += m2 * e.dx + m1 * h2f_hi(su1);
  av1 += m2 * e.dy + m1 * h2f_lo(su2);
  av2 += m2 * e.dz + m1 * h2f_hi(su2);
}

__global__ __launch_bounds__(128, 8) void node_kernel(
    const uint_t* __restrict__ merged, const EdgeRec* __restrict__ recs,
    const int* __restrict__ offsets, const float* __restrict__ Wr,
    const float* __restrict__ br, float* __restrict__ out, int N) {
  const int d = threadIdx.x;
  const int d3 = 3 * d;

  h2v wr0h[10], wr1h[10], wr2h[10];
#pragma unroll
  for (int q = 0; q < 10; ++q) {
    h2v w;
    w.x = (_Float16)Wr[(2 * q) * 384 + d3 + 0];
    w.y = (_Float16)Wr[(2 * q + 1) * 384 + d3 + 0];
    wr0h[q] = w;
    w.x = (_Float16)Wr[(2 * q) * 384 + d3 + 1];
    w.y = (_Float16)Wr[(2 * q + 1) * 384 + d3 + 1];
    wr1h[q] = w;
    w.x = (_Float16)Wr[(2 * q) * 384 + d3 + 2];
    w.y = (_Float16)Wr[(2 * q + 1) * 384 + d3 + 2];
    wr2h[q] = w;
  }
  const float br0 = br[d3 + 0];
  const float br1 = br[d3 + 1];
  const float br2 = br[d3 + 2];

  for (int nn = 0; nn < NODES_PER_BLOCK; ++nn) {
    const int n = blockIdx.x * NODES_PER_BLOCK + nn;
    if (n >= N) break;

    const int start = offsets[n];
    const int end = offsets[n + 1];

    float accs = 0.f, av0 = 0.f, av1 = 0.f, av2 = 0.f;

    int i = start;
    for (; i + 4 <= end; i += 4) {
      const int i0 = __builtin_amdgcn_readfirstlane(i);
      const EdgeRec& eA = recs[i0];
      const EdgeRec& eB = recs[i0 + 1];
      const EdgeRec& eC = recs[i0 + 2];
      const EdgeRec& eD = recs[i0 + 3];
      const uint_t* mpA = merged + (size_t)eA.src * 384 + d3;
      const uint_t* mpB = merged + (size_t)eB.src * 384 + d3;
      const uint_t* mpC = merged + (size_t)eC.src * 384 + d3;
      const uint_t* mpD = merged + (size_t)eD.src * 384 + d3;
      const uint_t suA0 = mpA[0], suA1 = mpA[1], suA2 = mpA[2];
      const uint_t suB0 = mpB[0], suB1 = mpB[1], suB2 = mpB[2];
      const uint_t suC0 = mpC[0], suC1 = mpC[1], suC2 = mpC[2];
      const uint_t suD0 = mpD[0], suD1 = mpD[1], suD2 = mpD[2];

      edge_body(eA, suA0, suA1, suA2, wr0h, wr1h, wr2h, br0, br1, br2, accs,
                av0, av1, av2);
      edge_body(eB, suB0, suB1, suB2, wr0h, wr1h, wr2h, br0, br1, br2, accs,
                av0, av1, av2);
      edge_body(eC, suC0, suC1, suC2, wr0h, wr1h, wr2h, br0, br1, br2, accs,
                av0, av1, av2);
      edge_body(eD, suD0, suD1, suD2, wr0h, wr1h, wr2h, br0, br1, br2, accs,
                av0, av1, av2);
    }
    for (; i < end; ++i) {
      const int i0 = __builtin_amdgcn_readfirstlane(i);
      const EdgeRec& eA = recs[i0];
      const uint_t* mpA = merged + (size_t)eA.src * 384 + d3;
      const uint_t suA0 = mpA[0], suA1 = mpA[1], suA2 = mpA[2];
      edge_body(eA, suA0, suA1, suA2, wr0h, wr1h, wr2h, br0, br1, br2, accs,
                av0, av1, av2);
    }

    out[(size_t)n * 384 + d3 + 0] = av0;
    out[(size_t)n * 384 + d3 + 1] = av1;
    out[(size_t)n * 384 + d3 + 2] = av2;
    out[(size_t)N * 384 + (size_t)n * 128 + d] = accs;
  }
}

// ---------------------------------------------------------------------------
extern "C" void kernel_launch(void* const* d_in, const int* in_sizes, int n_in,
                              void* d_out, int out_size, void* d_ws,
                              size_t ws_size, hipStream_t stream) {
  const float* vf  = (const float*)d_in[0];   // [N,128,3]
  const float* X   = (const float*)d_in[1];   // [N,128]
  const float* pos = (const float*)d_in[2];   // [N,3]
  const int* ei    = (const int*)d_in[3];     // [2,E]
  const float* W1  = (const float*)d_in[4];
  const float* b1  = (const float*)d_in[5];
  const float* W2  = (const float*)d_in[6];
  const float* b2  = (const float*)d_in[7];
  const float* Wr  = (const float*)d_in[8];
  const float* br  = (const float*)d_in[9];

  const int N = in_sizes[1] / D_DIM;
  const int E = in_sizes[3] / 2;
  const int* srcI = ei;
  const int* tgtI = ei + E;
  float* out = (float*)d_out;

  // workspace layout (16B-aligned chunks first)
  char* w = (char*)d_ws;
  EdgeRec* recs  = (EdgeRec*)w; w += (size_t)E * sizeof(EdgeRec);
  uint_t* merged = (uint_t*)w;  w += (size_t)N * 128 * 3 * sizeof(uint_t);
  int* counts    = (int*)w;     w += (size_t)N * sizeof(int);
  int* offsets   = (int*)w;     w += (size_t)(N + 1) * sizeof(int);
  int* cursor    = (int*)w;     w += (size_t)N * sizeof(int);

  const int nch = (N + 1023) / 1024;  // 49 for N=50000

  proj_kernel<<<(N + 63) / 64, 256, 0, stream>>>(X, W1, b1, W2, b2, vf, merged,
                                                 counts, N);
  hist_kernel<<<(E + 255) / 256, 256, 0, stream>>>(tgtI, counts, E);
  scan_block_kernel<<<nch, 256, 0, stream>>>(counts, offsets, cursor, N, E);
  edge_geom_kernel<<<(E + 255) / 256, 256, 0, stream>>>(pos, srcI, tgtI, cursor,
                                                        recs, E);
  node_kernel<<<(N + NODES_PER_BLOCK - 1) / NODES_PER_BLOCK, 128, 0, stream>>>(
      merged, recs, offsets, Wr, br, out, N);
}

// Round 18
// 291.547 us; speedup vs baseline: 1.0966x; 1.0966x over previous
//
#include <hip/hip_runtime.h>
#include <hip/hip_fp16.h>
#include <math.h>
#include <stddef.h>

#define D_DIM 128
#define NUM_RBF 20
typedef unsigned short ushort_t;
typedef unsigned int uint_t;
typedef _Float16 h2v __attribute__((ext_vector_type(2)));
typedef _Float16 half8_t __attribute__((ext_vector_type(8)));
typedef float float4_t __attribute__((ext_vector_type(4)));
constexpr float PI_F = 3.14159265358979323846f;
constexpr float CUT_OFF_F = 5.0f;
constexpr float SILU_SCALE_F = 1.0f / 0.6f;

__device__ __forceinline__ uint_t pack2h(float a, float b) {
  __half2 h2 = __floats2half2_rn(a, b);
  return *reinterpret_cast<uint_t*>(&h2);
}
__device__ __forceinline__ float h2f(ushort_t u) {
  __half h = __ushort_as_half(u);
  return __half2float(h);
}
__device__ __forceinline__ float h2f_lo(uint_t u) { return h2f((ushort_t)(u & 0xffffu)); }
__device__ __forceinline__ float h2f_hi(uint_t u) { return h2f((ushort_t)(u >> 16)); }
__device__ __forceinline__ h2v u2h2(uint_t u) {
  h2v r;
  __builtin_memcpy(&r, &u, 4);
  return r;
}

#if defined(__has_builtin)
#if __has_builtin(__builtin_amdgcn_fdot2)
#define HAVE_FDOT2 1
#endif
#endif

__device__ __forceinline__ float fdot2f(h2v a, h2v b, float c) {
#ifdef HAVE_FDOT2
  return __builtin_amdgcn_fdot2(a, b, c, false);
#else
  return c + (float)a.x * (float)b.x + (float)a.y * (float)b.y;
#endif
}

// 64B per-edge record: all wave-uniform data in one scalar-loadable block.
struct __align__(16) EdgeRec {
  uint_t rb[10];   // rbf packed fp16x2
  uint_t src;      // source node
  float dx, dy, dz;
  uint_t pad[2];
};

// ---------------------------------------------------------------------------
// MFMA node projection + merged-buffer build + counts zeroing (R13-verified).
// ---------------------------------------------------------------------------
__device__ __forceinline__ void stage_wt(const float* __restrict__ W,
                                         _Float16* __restrict__ Wt, int t,
                                         int f4stride, int f4base) {
  const float4* Wv = reinterpret_cast<const float4*>(W);
#pragma unroll
  for (int i = 0; i < 8; ++i) {
    int pid = t + i * 256;            // 0..2047: 64 k-pairs x 32 n-float4s
    int k = (pid >> 5) * 2;
    int nf = pid & 31;
    float4 a = Wv[(size_t)k * f4stride + f4base + nf];
    float4 b = Wv[(size_t)(k + 1) * f4stride + f4base + nf];
    const float av[4] = {a.x, a.y, a.z, a.w};
    const float bv[4] = {b.x, b.y, b.z, b.w};
    const int n0 = nf * 4;
#pragma unroll
    for (int j = 0; j < 4; ++j)
      *reinterpret_cast<uint_t*>(&Wt[(n0 + j) * 136 + k]) =
          pack2h(av[j], bv[j]);
  }
}

__global__ __launch_bounds__(256) void proj_kernel(
    const float* __restrict__ X, const float* __restrict__ W1,
    const float* __restrict__ b1, const float* __restrict__ W2,
    const float* __restrict__ b2, const float* __restrict__ vf,
    uint_t* __restrict__ merged, int* __restrict__ counts, int N) {
  __shared__ alignas(16) _Float16 smem[26112];  // Xs[64*136] + Wt[128*136]
  _Float16* Xs = smem;
  _Float16* Wt = smem + 8704;

  const int t = threadIdx.x;
  const int w = t >> 6;        // wave 0..3
  const int l = t & 63;        // lane
  const int nb = blockIdx.x * 64;

  // ---- fold-in: zero the CSR counts array ----
  {
    int z = blockIdx.x * 256 + t;
    if (z < N) counts[z] = 0;
  }

  // ---- stage X tile: [64][128] fp32 -> Xs[64][136] fp16 ----
  {
    const float4* Xv = reinterpret_cast<const float4*>(X);
#pragma unroll
    for (int i = 0; i < 8; ++i) {
      int g = t + i * 256;            // 0..2047
      int row = g >> 5, k0 = (g & 31) * 4;
      int node = nb + row;
      float4 v = (node < N) ? Xv[(size_t)nb * 32 + g]
                            : make_float4(0.f, 0.f, 0.f, 0.f);
      uint_t* dst = reinterpret_cast<uint_t*>(&Xs[row * 136 + k0]);
      dst[0] = pack2h(v.x, v.y);
      dst[1] = pack2h(v.z, v.w);
    }
  }
  stage_wt(W1, Wt, t, 32, 0);
  __syncthreads();

  const int arow = w * 16 + (l & 15);
  const int koff = (l >> 4) * 8;
  const int bcol = l & 15;

  // ---- phase 1: H = X @ W1 ----
  half8_t af[4];
#pragma unroll
  for (int s = 0; s < 4; ++s)
    af[s] = *reinterpret_cast<const half8_t*>(&Xs[arow * 136 + s * 32 + koff]);

  float4_t acc[8];
#pragma unroll
  for (int c = 0; c < 8; ++c) {
    float4_t a = {0.f, 0.f, 0.f, 0.f};
#pragma unroll
    for (int s = 0; s < 4; ++s) {
      half8_t bf = *reinterpret_cast<const half8_t*>(
          &Wt[(c * 16 + bcol) * 136 + s * 32 + koff]);
      a = __builtin_amdgcn_mfma_f32_16x16x32_f16(af[s], bf, a, 0, 0, 0);
    }
    acc[c] = a;
  }

  __syncthreads();  // all Xs/Wt reads done before overwrite

  // ---- bias + scaled-silu -> H (fp16) into Xs; stage W2 chunk 0 ----
#pragma unroll
  for (int c = 0; c < 8; ++c) {
    const int col = c * 16 + bcol;
    const float bv = b1[col];
#pragma unroll
    for (int r = 0; r < 4; ++r) {
      const int row = w * 16 + (l >> 4) * 4 + r;
      float hv = acc[c][r] + bv;
      hv = hv * SILU_SCALE_F / (1.0f + expf(-hv));
      Xs[row * 136 + col] = (_Float16)hv;
    }
  }
  stage_wt(W2, Wt, t, 96, 0);
  __syncthreads();

  // ---- phase 2: S = H @ W2 + b2, 3 col-chunks of 128; results in regs ----
  half8_t ha[4];
#pragma unroll
  for (int s = 0; s < 4; ++s)
    ha[s] = *reinterpret_cast<const half8_t*>(&Xs[arow * 136 + s * 32 + koff]);

  uint_t pk[3][8][2];   // packed fp16 results; fully static indexing
#pragma unroll
  for (int cn = 0; cn < 3; ++cn) {
    if (cn > 0) {
      __syncthreads();                // prev chunk's Wt reads done
      stage_wt(W2, Wt, t, 96, cn * 32);
      __syncthreads();
    }
#pragma unroll
    for (int c = 0; c < 8; ++c) {
      float4_t a = {0.f, 0.f, 0.f, 0.f};
#pragma unroll
      for (int s = 0; s < 4; ++s) {
        half8_t bf = *reinterpret_cast<const half8_t*>(
            &Wt[(c * 16 + bcol) * 136 + s * 32 + koff]);
        a = __builtin_amdgcn_mfma_f32_16x16x32_f16(ha[s], bf, a, 0, 0, 0);
      }
      const float bv = b2[cn * 128 + c * 16 + bcol];
      pk[cn][c][0] = pack2h(a[0] + bv, a[1] + bv);
      pk[cn][c][1] = pack2h(a[2] + bv, a[3] + bv);
    }
  }

  // ---- bounce S to LDS natural [64][392] ----
  __syncthreads();                    // all Wt reads done; smem reusable
  ushort_t* sh = reinterpret_cast<ushort_t*>(smem);
  {
    const int rbase = w * 16 + (l >> 4) * 4;
#pragma unroll
    for (int cn = 0; cn < 3; ++cn)
#pragma unroll
      for (int c = 0; c < 8; ++c) {
        const int gcol = cn * 128 + c * 16 + bcol;
        sh[(rbase + 0) * 392 + gcol] = (ushort_t)(pk[cn][c][0] & 0xffffu);
        sh[(rbase + 1) * 392 + gcol] = (ushort_t)(pk[cn][c][0] >> 16);
        sh[(rbase + 2) * 392 + gcol] = (ushort_t)(pk[cn][c][1] & 0xffffu);
        sh[(rbase + 3) * 392 + gcol] = (ushort_t)(pk[cn][c][1] >> 16);
      }
  }
  __syncthreads();

  // ---- merged build, vectorized 4 chans/work-item ----
#pragma unroll
  for (int k = 0; k < 8; ++k) {
    const int P = k * 256 + t;        // 0..2047
    const int ln = P >> 5;            // local node 0..63
    const int cg = (P & 31) * 4;      // chan group base 0,4,..,124
    const int node = nb + ln;
    if (node < N) {
      const ushort_t* sp = &sh[ln * 392 + 3 * cg];
      uint2 sa = *reinterpret_cast<const uint2*>(sp);
      uint2 sb = *reinterpret_cast<const uint2*>(sp + 4);
      uint2 sc = *reinterpret_cast<const uint2*>(sp + 8);
      ushort_t s12[12];
      s12[0] = (ushort_t)(sa.x & 0xffffu);  s12[1] = (ushort_t)(sa.x >> 16);
      s12[2] = (ushort_t)(sa.y & 0xffffu);  s12[3] = (ushort_t)(sa.y >> 16);
      s12[4] = (ushort_t)(sb.x & 0xffffu);  s12[5] = (ushort_t)(sb.x >> 16);
      s12[6] = (ushort_t)(sb.y & 0xffffu);  s12[7] = (ushort_t)(sb.y >> 16);
      s12[8] = (ushort_t)(sc.x & 0xffffu);  s12[9] = (ushort_t)(sc.x >> 16);
      s12[10] = (ushort_t)(sc.y & 0xffffu); s12[11] = (ushort_t)(sc.y >> 16);

      const float4* vp =
          reinterpret_cast<const float4*>(vf + ((size_t)node * 128 + cg) * 3);
      float4 v0 = vp[0], v1 = vp[1], v2 = vp[2];
      float vv[12] = {v0.x, v0.y, v0.z, v0.w, v1.x, v1.y,
                      v1.z, v1.w, v2.x, v2.y, v2.z, v2.w};

      uint_t o[12];
#pragma unroll
      for (int j = 0; j < 4; ++j) {
        o[3 * j + 0] = (uint_t)s12[3 * j] | ((uint_t)s12[3 * j + 1] << 16);
        o[3 * j + 1] =
            (uint_t)s12[3 * j + 2] |
            ((uint_t)__half_as_ushort(__float2half_rn(vv[3 * j])) << 16);
        o[3 * j + 2] = pack2h(vv[3 * j + 1], vv[3 * j + 2]);
      }
      uint_t* mp = merged + ((size_t)node * 128 + cg) * 3;
      *reinterpret_cast<uint4*>(mp) = make_uint4(o[0], o[1], o[2], o[3]);
      *reinterpret_cast<uint4*>(mp + 4) = make_uint4(o[4], o[5], o[6], o[7]);
      *reinterpret_cast<uint4*>(mp + 8) = make_uint4(o[8], o[9], o[10], o[11]);
    }
  }
}

// ---------------------------------------------------------------------------
// CSR build (R14 config: hist + chunk_sum + scan_block)
// ---------------------------------------------------------------------------
__global__ void hist_kernel(const int* __restrict__ tgt, int* __restrict__ counts,
                            int E) {
  int e = blockIdx.x * 256 + threadIdx.x;
  if (e < E) atomicAdd(&counts[tgt[e]], 1);
}

__global__ void chunk_sum_kernel(const int* __restrict__ counts,
                                 int* __restrict__ chunk_sums, int N) {
  __shared__ int red[256];
  int b = blockIdx.x, t = threadIdx.x;
  int base = b * 1024 + t * 4;
  int s = 0;
#pragma unroll
  for (int j = 0; j < 4; ++j) s += (base + j < N) ? counts[base + j] : 0;
  red[t] = s;
  __syncthreads();
  for (int off = 128; off > 0; off >>= 1) {
    if (t < off) red[t] += red[t + off];
    __syncthreads();
  }
  if (t == 0) chunk_sums[b] = red[0];
}

__global__ void scan_block_kernel(const int* __restrict__ counts,
                                  const int* __restrict__ chunk_sums,
                                  int* __restrict__ offsets,
                                  int* __restrict__ cursor, int N, int E) {
  __shared__ int part[256];
  __shared__ int chunk_base_sh;
  int b = blockIdx.x, t = threadIdx.x;
  if (t < 64) {
    int v = (t < b) ? chunk_sums[t] : 0;
#pragma unroll
    for (int off = 32; off > 0; off >>= 1) v += __shfl_down(v, off);
    if (t == 0) chunk_base_sh = v;
  }
  int base = b * 1024 + t * 4;
  int v[4];
#pragma unroll
  for (int j = 0; j < 4; ++j) v[j] = (base + j < N) ? counts[base + j] : 0;
  int local = v[0] + v[1] + v[2] + v[3];
  part[t] = local;
  __syncthreads();
  for (int off = 1; off < 256; off <<= 1) {
    int x = 0;
    if (t >= off) x = part[t - off];
    __syncthreads();
    if (t >= off) part[t] += x;
    __syncthreads();
  }
  int run = chunk_base_sh + (part[t] - local);
#pragma unroll
  for (int j = 0; j < 4; ++j) {
    if (base + j < N) {
      offsets[base + j] = run;
      cursor[base + j] = run;
      run += v[j];
    }
  }
  if (b == 0 && t == 0) offsets[N] = E;
}

// ---------------------------------------------------------------------------
// Fused edge geometry + CSR scatter into 64B EdgeRec records.
// ---------------------------------------------------------------------------
__global__ void edge_geom_kernel(const float* __restrict__ pos,
                                 const int* __restrict__ src,
                                 const int* __restrict__ tgt,
                                 int* __restrict__ cursor,
                                 EdgeRec* __restrict__ recs, int E) {
  int e = blockIdx.x * 256 + threadIdx.x;
  if (e >= E) return;
  const int sn = src[e];
  const int tn = tgt[e];
  const float rx = pos[tn * 3 + 0] - pos[sn * 3 + 0];
  const float ry = pos[tn * 3 + 1] - pos[sn * 3 + 1];
  const float rz = pos[tn * 3 + 2] - pos[sn * 3 + 2];
  const float dist = sqrtf(rx * rx + ry * ry + rz * rz);
  const float inv = 1.0f / dist;

  const float ang = dist * (PI_F / CUT_OFF_F);
  float s1, c1;
  sincosf(ang, &s1, &c1);
  float sk = s1, ck = c1;
  float rb[NUM_RBF];
  rb[0] = s1 * inv;
#pragma unroll
  for (int r = 1; r < NUM_RBF; ++r) {
    float sn2 = sk * c1 + ck * s1;
    ck = ck * c1 - sk * s1;
    sk = sn2;
    rb[r] = sk * inv;
  }

  const int p = atomicAdd(&cursor[tn], 1);
  uint_t us[10];
#pragma unroll
  for (int q = 0; q < 10; ++q) us[q] = pack2h(rb[2 * q], rb[2 * q + 1]);
  uint_t* o = reinterpret_cast<uint_t*>(&recs[p]);
  *reinterpret_cast<uint4*>(o) = make_uint4(us[0], us[1], us[2], us[3]);
  *reinterpret_cast<uint4*>(o + 4) = make_uint4(us[4], us[5], us[6], us[7]);
  *reinterpret_cast<uint4*>(o + 8) =
      make_uint4(us[8], us[9], (uint_t)sn, __float_as_uint(rx * inv));
  *reinterpret_cast<uint4*>(o + 12) =
      make_uint4(__float_as_uint(ry * inv), __float_as_uint(rz * inv), 0u, 0u);
}

// ---------------------------------------------------------------------------
// Node gather. One wave-uniform 64B record + 3 per-lane merged dwords per
// edge. x4 unroll with upfront loads; v_cos cutoff. NPB=16, default
// launch bounds (R17's min-waves=8 hint capped VGPR at 32 -> spills).
// ---------------------------------------------------------------------------
#define NODES_PER_BLOCK 16

__device__ __forceinline__ float cutoff_f(float x) {
#if defined(__has_builtin)
#if __has_builtin(__builtin_amdgcn_cosf)
  float c = __builtin_amdgcn_cosf(x * 0.1f);   // v_cos_f32: revolutions
#else
  float c = __cosf(x * (PI_F / CUT_OFF_F));
#endif
#else
  float c = __cosf(x * (PI_F / CUT_OFF_F));
#endif
  return (x < CUT_OFF_F) ? 0.5f + 0.5f * c : 0.f;
}

__device__ __forceinline__ void edge_body(const EdgeRec& e, uint_t su0,
                                          uint_t su1, uint_t su2,
                                          const h2v* wr0h, const h2v* wr1h,
                                          const h2v* wr2h, float br0, float br1,
                                          float br2, float& accs, float& av0,
                                          float& av1, float& av2) {
  float f0 = br0, f1 = br1, f2 = br2;
#pragma unroll
  for (int q = 0; q < 10; ++q) {
    h2v r = u2h2(e.rb[q]);
    f0 = fdot2f(r, wr0h[q], f0);
    f1 = fdot2f(r, wr1h[q], f1);
    f2 = fdot2f(r, wr2h[q], f2);
  }
  f0 = cutoff_f(f0);
  f1 = cutoff_f(f1);
  f2 = cutoff_f(f2);
  const float m0 = h2f_lo(su0) * f0;
  const float m1 = h2f_hi(su0) * f1;
  const float m2 = h2f_lo(su1) * f2;
  accs += m0;
  av0 += m2 * e.dx + m1 * h2f_hi(su1);
  av1 += m2 * e.dy + m1 * h2f_lo(su2);
  av2 += m2 * e.dz + m1 * h2f_hi(su2);
}

__global__ __launch_bounds__(128) void node_kernel(
    const uint_t* __restrict__ merged, const EdgeRec* __restrict__ recs,
    const int* __restrict__ offsets, const float* __restrict__ Wr,
    const float* __restrict__ br, float* __restrict__ out, int N) {
  const int d = threadIdx.x;
  const int d3 = 3 * d;

  h2v wr0h[10], wr1h[10], wr2h[10];
#pragma unroll
  for (int q = 0; q < 10; ++q) {
    h2v w;
    w.x = (_Float16)Wr[(2 * q) * 384 + d3 + 0];
    w.y = (_Float16)Wr[(2 * q + 1) * 384 + d3 + 0];
    wr0h[q] = w;
    w.x = (_Float16)Wr[(2 * q) * 384 + d3 + 1];
    w.y = (_Float16)Wr[(2 * q + 1) * 384 + d3 + 1];
    wr1h[q] = w;
    w.x = (_Float16)Wr[(2 * q) * 384 + d3 + 2];
    w.y = (_Float16)Wr[(2 * q + 1) * 384 + d3 + 2];
    wr2h[q] = w;
  }
  const float br0 = br[d3 + 0];
  const float br1 = br[d3 + 1];
  const float br2 = br[d3 + 2];

  for (int nn = 0; nn < NODES_PER_BLOCK; ++nn) {
    const int n = blockIdx.x * NODES_PER_BLOCK + nn;
    if (n >= N) break;

    const int start = offsets[n];
    const int end = offsets[n + 1];

    float accs = 0.f, av0 = 0.f, av1 = 0.f, av2 = 0.f;

    int i = start;
    for (; i + 4 <= end; i += 4) {
      const int i0 = __builtin_amdgcn_readfirstlane(i);
      const EdgeRec& eA = recs[i0];
      const EdgeRec& eB = recs[i0 + 1];
      const EdgeRec& eC = recs[i0 + 2];
      const EdgeRec& eD = recs[i0 + 3];
      const uint_t* mpA = merged + (size_t)eA.src * 384 + d3;
      const uint_t* mpB = merged + (size_t)eB.src * 384 + d3;
      const uint_t* mpC = merged + (size_t)eC.src * 384 + d3;
      const uint_t* mpD = merged + (size_t)eD.src * 384 + d3;
      const uint_t suA0 = mpA[0], suA1 = mpA[1], suA2 = mpA[2];
      const uint_t suB0 = mpB[0], suB1 = mpB[1], suB2 = mpB[2];
      const uint_t suC0 = mpC[0], suC1 = mpC[1], suC2 = mpC[2];
      const uint_t suD0 = mpD[0], suD1 = mpD[1], suD2 = mpD[2];

      edge_body(eA, suA0, suA1, suA2, wr0h, wr1h, wr2h, br0, br1, br2, accs,
                av0, av1, av2);
      edge_body(eB, suB0, suB1, suB2, wr0h, wr1h, wr2h, br0, br1, br2, accs,
                av0, av1, av2);
      edge_body(eC, suC0, suC1, suC2, wr0h, wr1h, wr2h, br0, br1, br2, accs,
                av0, av1, av2);
      edge_body(eD, suD0, suD1, suD2, wr0h, wr1h, wr2h, br0, br1, br2, accs,
                av0, av1, av2);
    }
    for (; i < end; ++i) {
      const int i0 = __builtin_amdgcn_readfirstlane(i);
      const EdgeRec& eA = recs[i0];
      const uint_t* mpA = merged + (size_t)eA.src * 384 + d3;
      const uint_t suA0 = mpA[0], suA1 = mpA[1], suA2 = mpA[2];
      edge_body(eA, suA0, suA1, suA2, wr0h, wr1h, wr2h, br0, br1, br2, accs,
                av0, av1, av2);
    }

    out[(size_t)n * 384 + d3 + 0] = av0;
    out[(size_t)n * 384 + d3 + 1] = av1;
    out[(size_t)n * 384 + d3 + 2] = av2;
    out[(size_t)N * 384 + (size_t)n * 128 + d] = accs;
  }
}

// ---------------------------------------------------------------------------
extern "C" void kernel_launch(void* const* d_in, const int* in_sizes, int n_in,
                              void* d_out, int out_size, void* d_ws,
                              size_t ws_size, hipStream_t stream) {
  const float* vf  = (const float*)d_in[0];   // [N,128,3]
  const float* X   = (const float*)d_in[1];   // [N,128]
  const float* pos = (const float*)d_in[2];   // [N,3]
  const int* ei    = (const int*)d_in[3];     // [2,E]
  const float* W1  = (const float*)d_in[4];
  const float* b1  = (const float*)d_in[5];
  const float* W2  = (const float*)d_in[6];
  const float* b2  = (const float*)d_in[7];
  const float* Wr  = (const float*)d_in[8];
  const float* br  = (const float*)d_in[9];

  const int N = in_sizes[1] / D_DIM;
  const int E = in_sizes[3] / 2;
  const int* srcI = ei;
  const int* tgtI = ei + E;
  float* out = (float*)d_out;

  // workspace layout (16B-aligned chunks first)
  char* w = (char*)d_ws;
  EdgeRec* recs  = (EdgeRec*)w; w += (size_t)E * sizeof(EdgeRec);
  uint_t* merged = (uint_t*)w;  w += (size_t)N * 128 * 3 * sizeof(uint_t);
  int* counts    = (int*)w;     w += (size_t)N * sizeof(int);
  int* offsets   = (int*)w;     w += (size_t)(N + 1) * sizeof(int);
  int* cursor    = (int*)w;     w += (size_t)N * sizeof(int);
  int* chunks    = (int*)w;     w += 64 * sizeof(int);

  const int nch = (N + 1023) / 1024;  // 49 for N=50000 (<= 64 required)

  proj_kernel<<<(N + 63) / 64, 256, 0, stream>>>(X, W1, b1, W2, b2, vf, merged,
                                                 counts, N);
  hist_kernel<<<(E + 255) / 256, 256, 0, stream>>>(tgtI, counts, E);
  chunk_sum_kernel<<<nch, 256, 0, stream>>>(counts, chunks, N);
  scan_block_kernel<<<nch, 256, 0, stream>>>(counts, chunks, offsets, cursor,
                                             N, E);
  edge_geom_kernel<<<(E + 255) / 256, 256, 0, stream>>>(pos, srcI, tgtI, cursor,
                                                        recs, E);
  node_kernel<<<(N + NODES_PER_BLOCK - 1) / NODES_PER_BLOCK, 128, 0, stream>>>(
      merged, recs, offsets, Wr, br, out, N);
}

// Round 19
// 274.617 us; speedup vs baseline: 1.1642x; 1.0616x over previous
//
#include <hip/hip_runtime.h>
#include <hip/hip_fp16.h>
#include <math.h>
#include <stddef.h>

#define D_DIM 128
#define NUM_RBF 20
typedef unsigned short ushort_t;
typedef unsigned int uint_t;
typedef _Float16 h2v __attribute__((ext_vector_type(2)));
typedef _Float16 half8_t __attribute__((ext_vector_type(8)));
typedef float float4_t __attribute__((ext_vector_type(4)));
constexpr float PI_F = 3.14159265358979323846f;
constexpr float CUT_OFF_F = 5.0f;
constexpr float SILU_SCALE_F = 1.0f / 0.6f;

__device__ __forceinline__ uint_t pack2h(float a, float b) {
  __half2 h2 = __floats2half2_rn(a, b);
  return *reinterpret_cast<uint_t*>(&h2);
}
__device__ __forceinline__ float h2f(ushort_t u) {
  __half h = __ushort_as_half(u);
  return __half2float(h);
}
__device__ __forceinline__ float h2f_lo(uint_t u) { return h2f((ushort_t)(u & 0xffffu)); }
__device__ __forceinline__ float h2f_hi(uint_t u) { return h2f((ushort_t)(u >> 16)); }
__device__ __forceinline__ h2v u2h2(uint_t u) {
  h2v r;
  __builtin_memcpy(&r, &u, 4);
  return r;
}

#if defined(__has_builtin)
#if __has_builtin(__builtin_amdgcn_fdot2)
#define HAVE_FDOT2 1
#endif
#endif

__device__ __forceinline__ float fdot2f(h2v a, h2v b, float c) {
#ifdef HAVE_FDOT2
  return __builtin_amdgcn_fdot2(a, b, c, false);
#else
  return c + (float)a.x * (float)b.x + (float)a.y * (float)b.y;
#endif
}

// 64B per-edge record: all wave-uniform data in one scalar-loadable block.
struct __align__(16) EdgeRec {
  uint_t rb[10];   // rbf packed fp16x2
  uint_t src;      // source node
  float dx, dy, dz;
  uint_t pad[2];
};

// ---------------------------------------------------------------------------
// MFMA node projection + merged-buffer build + counts zeroing (R13-verified).
// ---------------------------------------------------------------------------
__device__ __forceinline__ void stage_wt(const float* __restrict__ W,
                                         _Float16* __restrict__ Wt, int t,
                                         int f4stride, int f4base) {
  const float4* Wv = reinterpret_cast<const float4*>(W);
#pragma unroll
  for (int i = 0; i < 8; ++i) {
    int pid = t + i * 256;            // 0..2047: 64 k-pairs x 32 n-float4s
    int k = (pid >> 5) * 2;
    int nf = pid & 31;
    float4 a = Wv[(size_t)k * f4stride + f4base + nf];
    float4 b = Wv[(size_t)(k + 1) * f4stride + f4base + nf];
    const float av[4] = {a.x, a.y, a.z, a.w};
    const float bv[4] = {b.x, b.y, b.z, b.w};
    const int n0 = nf * 4;
#pragma unroll
    for (int j = 0; j < 4; ++j)
      *reinterpret_cast<uint_t*>(&Wt[(n0 + j) * 136 + k]) =
          pack2h(av[j], bv[j]);
  }
}

__global__ __launch_bounds__(256) void proj_kernel(
    const float* __restrict__ X, const float* __restrict__ W1,
    const float* __restrict__ b1, const float* __restrict__ W2,
    const float* __restrict__ b2, const float* __restrict__ vf,
    uint_t* __restrict__ merged, int* __restrict__ counts, int N) {
  __shared__ alignas(16) _Float16 smem[26112];  // Xs[64*136] + Wt[128*136]
  _Float16* Xs = smem;
  _Float16* Wt = smem + 8704;

  const int t = threadIdx.x;
  const int w = t >> 6;        // wave 0..3
  const int l = t & 63;        // lane
  const int nb = blockIdx.x * 64;

  // ---- fold-in: zero the CSR counts array ----
  {
    int z = blockIdx.x * 256 + t;
    if (z < N) counts[z] = 0;
  }

  // ---- stage X tile: [64][128] fp32 -> Xs[64][136] fp16 ----
  {
    const float4* Xv = reinterpret_cast<const float4*>(X);
#pragma unroll
    for (int i = 0; i < 8; ++i) {
      int g = t + i * 256;            // 0..2047
      int row = g >> 5, k0 = (g & 31) * 4;
      int node = nb + row;
      float4 v = (node < N) ? Xv[(size_t)nb * 32 + g]
                            : make_float4(0.f, 0.f, 0.f, 0.f);
      uint_t* dst = reinterpret_cast<uint_t*>(&Xs[row * 136 + k0]);
      dst[0] = pack2h(v.x, v.y);
      dst[1] = pack2h(v.z, v.w);
    }
  }
  stage_wt(W1, Wt, t, 32, 0);
  __syncthreads();

  const int arow = w * 16 + (l & 15);
  const int koff = (l >> 4) * 8;
  const int bcol = l & 15;

  // ---- phase 1: H = X @ W1 ----
  half8_t af[4];
#pragma unroll
  for (int s = 0; s < 4; ++s)
    af[s] = *reinterpret_cast<const half8_t*>(&Xs[arow * 136 + s * 32 + koff]);

  float4_t acc[8];
#pragma unroll
  for (int c = 0; c < 8; ++c) {
    float4_t a = {0.f, 0.f, 0.f, 0.f};
#pragma unroll
    for (int s = 0; s < 4; ++s) {
      half8_t bf = *reinterpret_cast<const half8_t*>(
          &Wt[(c * 16 + bcol) * 136 + s * 32 + koff]);
      a = __builtin_amdgcn_mfma_f32_16x16x32_f16(af[s], bf, a, 0, 0, 0);
    }
    acc[c] = a;
  }

  __syncthreads();  // all Xs/Wt reads done before overwrite

  // ---- bias + scaled-silu -> H (fp16) into Xs; stage W2 chunk 0 ----
#pragma unroll
  for (int c = 0; c < 8; ++c) {
    const int col = c * 16 + bcol;
    const float bv = b1[col];
#pragma unroll
    for (int r = 0; r < 4; ++r) {
      const int row = w * 16 + (l >> 4) * 4 + r;
      float hv = acc[c][r] + bv;
      hv = hv * SILU_SCALE_F / (1.0f + expf(-hv));
      Xs[row * 136 + col] = (_Float16)hv;
    }
  }
  stage_wt(W2, Wt, t, 96, 0);
  __syncthreads();

  // ---- phase 2: S = H @ W2 + b2, 3 col-chunks of 128; results in regs ----
  half8_t ha[4];
#pragma unroll
  for (int s = 0; s < 4; ++s)
    ha[s] = *reinterpret_cast<const half8_t*>(&Xs[arow * 136 + s * 32 + koff]);

  uint_t pk[3][8][2];   // packed fp16 results; fully static indexing
#pragma unroll
  for (int cn = 0; cn < 3; ++cn) {
    if (cn > 0) {
      __syncthreads();                // prev chunk's Wt reads done
      stage_wt(W2, Wt, t, 96, cn * 32);
      __syncthreads();
    }
#pragma unroll
    for (int c = 0; c < 8; ++c) {
      float4_t a = {0.f, 0.f, 0.f, 0.f};
#pragma unroll
      for (int s = 0; s < 4; ++s) {
        half8_t bf = *reinterpret_cast<const half8_t*>(
            &Wt[(c * 16 + bcol) * 136 + s * 32 + koff]);
        a = __builtin_amdgcn_mfma_f32_16x16x32_f16(ha[s], bf, a, 0, 0, 0);
      }
      const float bv = b2[cn * 128 + c * 16 + bcol];
      pk[cn][c][0] = pack2h(a[0] + bv, a[1] + bv);
      pk[cn][c][1] = pack2h(a[2] + bv, a[3] + bv);
    }
  }

  // ---- bounce S to LDS natural [64][392] ----
  __syncthreads();                    // all Wt reads done; smem reusable
  ushort_t* sh = reinterpret_cast<ushort_t*>(smem);
  {
    const int rbase = w * 16 + (l >> 4) * 4;
#pragma unroll
    for (int cn = 0; cn < 3; ++cn)
#pragma unroll
      for (int c = 0; c < 8; ++c) {
        const int gcol = cn * 128 + c * 16 + bcol;
        sh[(rbase + 0) * 392 + gcol] = (ushort_t)(pk[cn][c][0] & 0xffffu);
        sh[(rbase + 1) * 392 + gcol] = (ushort_t)(pk[cn][c][0] >> 16);
        sh[(rbase + 2) * 392 + gcol] = (ushort_t)(pk[cn][c][1] & 0xffffu);
        sh[(rbase + 3) * 392 + gcol] = (ushort_t)(pk[cn][c][1] >> 16);
      }
  }
  __syncthreads();

  // ---- merged build, vectorized 4 chans/work-item ----
#pragma unroll
  for (int k = 0; k < 8; ++k) {
    const int P = k * 256 + t;        // 0..2047
    const int ln = P >> 5;            // local node 0..63
    const int cg = (P & 31) * 4;      // chan group base 0,4,..,124
    const int node = nb + ln;
    if (node < N) {
      const ushort_t* sp = &sh[ln * 392 + 3 * cg];
      uint2 sa = *reinterpret_cast<const uint2*>(sp);
      uint2 sb = *reinterpret_cast<const uint2*>(sp + 4);
      uint2 sc = *reinterpret_cast<const uint2*>(sp + 8);
      ushort_t s12[12];
      s12[0] = (ushort_t)(sa.x & 0xffffu);  s12[1] = (ushort_t)(sa.x >> 16);
      s12[2] = (ushort_t)(sa.y & 0xffffu);  s12[3] = (ushort_t)(sa.y >> 16);
      s12[4] = (ushort_t)(sb.x & 0xffffu);  s12[5] = (ushort_t)(sb.x >> 16);
      s12[6] = (ushort_t)(sb.y & 0xffffu);  s12[7] = (ushort_t)(sb.y >> 16);
      s12[8] = (ushort_t)(sc.x & 0xffffu);  s12[9] = (ushort_t)(sc.x >> 16);
      s12[10] = (ushort_t)(sc.y & 0xffffu); s12[11] = (ushort_t)(sc.y >> 16);

      const float4* vp =
          reinterpret_cast<const float4*>(vf + ((size_t)node * 128 + cg) * 3);
      float4 v0 = vp[0], v1 = vp[1], v2 = vp[2];
      float vv[12] = {v0.x, v0.y, v0.z, v0.w, v1.x, v1.y,
                      v1.z, v1.w, v2.x, v2.y, v2.z, v2.w};

      uint_t o[12];
#pragma unroll
      for (int j = 0; j < 4; ++j) {
        o[3 * j + 0] = (uint_t)s12[3 * j] | ((uint_t)s12[3 * j + 1] << 16);
        o[3 * j + 1] =
            (uint_t)s12[3 * j + 2] |
            ((uint_t)__half_as_ushort(__float2half_rn(vv[3 * j])) << 16);
        o[3 * j + 2] = pack2h(vv[3 * j + 1], vv[3 * j + 2]);
      }
      uint_t* mp = merged + ((size_t)node * 128 + cg) * 3;
      *reinterpret_cast<uint4*>(mp) = make_uint4(o[0], o[1], o[2], o[3]);
      *reinterpret_cast<uint4*>(mp + 4) = make_uint4(o[4], o[5], o[6], o[7]);
      *reinterpret_cast<uint4*>(mp + 8) = make_uint4(o[8], o[9], o[10], o[11]);
    }
  }
}

// ---------------------------------------------------------------------------
// CSR build (R14 config: hist + chunk_sum + scan_block)
// ---------------------------------------------------------------------------
__global__ void hist_kernel(const int* __restrict__ tgt, int* __restrict__ counts,
                            int E) {
  int e = blockIdx.x * 256 + threadIdx.x;
  if (e < E) atomicAdd(&counts[tgt[e]], 1);
}

__global__ void chunk_sum_kernel(const int* __restrict__ counts,
                                 int* __restrict__ chunk_sums, int N) {
  __shared__ int red[256];
  int b = blockIdx.x, t = threadIdx.x;
  int base = b * 1024 + t * 4;
  int s = 0;
#pragma unroll
  for (int j = 0; j < 4; ++j) s += (base + j < N) ? counts[base + j] : 0;
  red[t] = s;
  __syncthreads();
  for (int off = 128; off > 0; off >>= 1) {
    if (t < off) red[t] += red[t + off];
    __syncthreads();
  }
  if (t == 0) chunk_sums[b] = red[0];
}

__global__ void scan_block_kernel(const int* __restrict__ counts,
                                  const int* __restrict__ chunk_sums,
                                  int* __restrict__ offsets,
                                  int* __restrict__ cursor, int N, int E) {
  __shared__ int part[256];
  __shared__ int chunk_base_sh;
  int b = blockIdx.x, t = threadIdx.x;
  if (t < 64) {
    int v = (t < b) ? chunk_sums[t] : 0;
#pragma unroll
    for (int off = 32; off > 0; off >>= 1) v += __shfl_down(v, off);
    if (t == 0) chunk_base_sh = v;
  }
  int base = b * 1024 + t * 4;
  int v[4];
#pragma unroll
  for (int j = 0; j < 4; ++j) v[j] = (base + j < N) ? counts[base + j] : 0;
  int local = v[0] + v[1] + v[2] + v[3];
  part[t] = local;
  __syncthreads();
  for (int off = 1; off < 256; off <<= 1) {
    int x = 0;
    if (t >= off) x = part[t - off];
    __syncthreads();
    if (t >= off) part[t] += x;
    __syncthreads();
  }
  int run = chunk_base_sh + (part[t] - local);
#pragma unroll
  for (int j = 0; j < 4; ++j) {
    if (base + j < N) {
      offsets[base + j] = run;
      cursor[base + j] = run;
      run += v[j];
    }
  }
  if (b == 0 && t == 0) offsets[N] = E;
}

// ---------------------------------------------------------------------------
// Fused edge geometry + CSR scatter into 64B EdgeRec records.
// ---------------------------------------------------------------------------
__global__ void edge_geom_kernel(const float* __restrict__ pos,
                                 const int* __restrict__ src,
                                 const int* __restrict__ tgt,
                                 int* __restrict__ cursor,
                                 EdgeRec* __restrict__ recs, int E) {
  int e = blockIdx.x * 256 + threadIdx.x;
  if (e >= E) return;
  const int sn = src[e];
  const int tn = tgt[e];
  const float rx = pos[tn * 3 + 0] - pos[sn * 3 + 0];
  const float ry = pos[tn * 3 + 1] - pos[sn * 3 + 1];
  const float rz = pos[tn * 3 + 2] - pos[sn * 3 + 2];
  const float dist = sqrtf(rx * rx + ry * ry + rz * rz);
  const float inv = 1.0f / dist;

  const float ang = dist * (PI_F / CUT_OFF_F);
  float s1, c1;
  sincosf(ang, &s1, &c1);
  float sk = s1, ck = c1;
  float rb[NUM_RBF];
  rb[0] = s1 * inv;
#pragma unroll
  for (int r = 1; r < NUM_RBF; ++r) {
    float sn2 = sk * c1 + ck * s1;
    ck = ck * c1 - sk * s1;
    sk = sn2;
    rb[r] = sk * inv;
  }

  const int p = atomicAdd(&cursor[tn], 1);
  uint_t us[10];
#pragma unroll
  for (int q = 0; q < 10; ++q) us[q] = pack2h(rb[2 * q], rb[2 * q + 1]);
  uint_t* o = reinterpret_cast<uint_t*>(&recs[p]);
  *reinterpret_cast<uint4*>(o) = make_uint4(us[0], us[1], us[2], us[3]);
  *reinterpret_cast<uint4*>(o + 4) = make_uint4(us[4], us[5], us[6], us[7]);
  *reinterpret_cast<uint4*>(o + 8) =
      make_uint4(us[8], us[9], (uint_t)sn, __float_as_uint(rx * inv));
  *reinterpret_cast<uint4*>(o + 12) =
      make_uint4(__float_as_uint(ry * inv), __float_as_uint(rz * inv), 0u, 0u);
}

// ---------------------------------------------------------------------------
// Node gather (R14 config, session-best 274 us). One wave-uniform 64B record
// + 3 per-lane merged dwords per edge. x4 unroll with upfront loads; v_cos
// cutoff. NPB=8 (measured optimum: 16 dropped occupancy 42->37%, node +12us).
// ---------------------------------------------------------------------------
#define NODES_PER_BLOCK 8

__device__ __forceinline__ float cutoff_f(float x) {
#if defined(__has_builtin)
#if __has_builtin(__builtin_amdgcn_cosf)
  float c = __builtin_amdgcn_cosf(x * 0.1f);   // v_cos_f32: revolutions
#else
  float c = __cosf(x * (PI_F / CUT_OFF_F));
#endif
#else
  float c = __cosf(x * (PI_F / CUT_OFF_F));
#endif
  return (x < CUT_OFF_F) ? 0.5f + 0.5f * c : 0.f;
}

__device__ __forceinline__ void edge_body(const EdgeRec& e, uint_t su0,
                                          uint_t su1, uint_t su2,
                                          const h2v* wr0h, const h2v* wr1h,
                                          const h2v* wr2h, float br0, float br1,
                                          float br2, float& accs, float& av0,
                                          float& av1, float& av2) {
  float f0 = br0, f1 = br1, f2 = br2;
#pragma unroll
  for (int q = 0; q < 10; ++q) {
    h2v r = u2h2(e.rb[q]);
    f0 = fdot2f(r, wr0h[q], f0);
    f1 = fdot2f(r, wr1h[q], f1);
    f2 = fdot2f(r, wr2h[q], f2);
  }
  f0 = cutoff_f(f0);
  f1 = cutoff_f(f1);
  f2 = cutoff_f(f2);
  const float m0 = h2f_lo(su0) * f0;
  const float m1 = h2f_hi(su0) * f1;
  const float m2 = h2f_lo(su1) * f2;
  accs += m0;
  av0 += m2 * e.dx + m1 * h2f_hi(su1);
  av1 += m2 * e.dy + m1 * h2f_lo(su2);
  av2 += m2 * e.dz + m1 * h2f_hi(su2);
}

__global__ __launch_bounds__(128) void node_kernel(
    const uint_t* __restrict__ merged, const EdgeRec* __restrict__ recs,
    const int* __restrict__ offsets, const float* __restrict__ Wr,
    const float* __restrict__ br, float* __restrict__ out, int N) {
  const int d = threadIdx.x;
  const int d3 = 3 * d;

  h2v wr0h[10], wr1h[10], wr2h[10];
#pragma unroll
  for (int q = 0; q < 10; ++q) {
    h2v w;
    w.x = (_Float16)Wr[(2 * q) * 384 + d3 + 0];
    w.y = (_Float16)Wr[(2 * q + 1) * 384 + d3 + 0];
    wr0h[q] = w;
    w.x = (_Float16)Wr[(2 * q) * 384 + d3 + 1];
    w.y = (_Float16)Wr[(2 * q + 1) * 384 + d3 + 1];
    wr1h[q] = w;
    w.x = (_Float16)Wr[(2 * q) * 384 + d3 + 2];
    w.y = (_Float16)Wr[(2 * q + 1) * 384 + d3 + 2];
    wr2h[q] = w;
  }
  const float br0 = br[d3 + 0];
  const float br1 = br[d3 + 1];
  const float br2 = br[d3 + 2];

  for (int nn = 0; nn < NODES_PER_BLOCK; ++nn) {
    const int n = blockIdx.x * NODES_PER_BLOCK + nn;
    if (n >= N) break;

    const int start = offsets[n];
    const int end = offsets[n + 1];

    float accs = 0.f, av0 = 0.f, av1 = 0.f, av2 = 0.f;

    int i = start;
    for (; i + 4 <= end; i += 4) {
      const int i0 = __builtin_amdgcn_readfirstlane(i);
      const EdgeRec& eA = recs[i0];
      const EdgeRec& eB = recs[i0 + 1];
      const EdgeRec& eC = recs[i0 + 2];
      const EdgeRec& eD = recs[i0 + 3];
      const uint_t* mpA = merged + (size_t)eA.src * 384 + d3;
      const uint_t* mpB = merged + (size_t)eB.src * 384 + d3;
      const uint_t* mpC = merged + (size_t)eC.src * 384 + d3;
      const uint_t* mpD = merged + (size_t)eD.src * 384 + d3;
      const uint_t suA0 = mpA[0], suA1 = mpA[1], suA2 = mpA[2];
      const uint_t suB0 = mpB[0], suB1 = mpB[1], suB2 = mpB[2];
      const uint_t suC0 = mpC[0], suC1 = mpC[1], suC2 = mpC[2];
      const uint_t suD0 = mpD[0], suD1 = mpD[1], suD2 = mpD[2];

      edge_body(eA, suA0, suA1, suA2, wr0h, wr1h, wr2h, br0, br1, br2, accs,
                av0, av1, av2);
      edge_body(eB, suB0, suB1, suB2, wr0h, wr1h, wr2h, br0, br1, br2, accs,
                av0, av1, av2);
      edge_body(eC, suC0, suC1, suC2, wr0h, wr1h, wr2h, br0, br1, br2, accs,
                av0, av1, av2);
      edge_body(eD, suD0, suD1, suD2, wr0h, wr1h, wr2h, br0, br1, br2, accs,
                av0, av1, av2);
    }
    for (; i < end; ++i) {
      const int i0 = __builtin_amdgcn_readfirstlane(i);
      const EdgeRec& eA = recs[i0];
      const uint_t* mpA = merged + (size_t)eA.src * 384 + d3;
      const uint_t suA0 = mpA[0], suA1 = mpA[1], suA2 = mpA[2];
      edge_body(eA, suA0, suA1, suA2, wr0h, wr1h, wr2h, br0, br1, br2, accs,
                av0, av1, av2);
    }

    out[(size_t)n * 384 + d3 + 0] = av0;
    out[(size_t)n * 384 + d3 + 1] = av1;
    out[(size_t)n * 384 + d3 + 2] = av2;
    out[(size_t)N * 384 + (size_t)n * 128 + d] = accs;
  }
}

// ---------------------------------------------------------------------------
extern "C" void kernel_launch(void* const* d_in, const int* in_sizes, int n_in,
                              void* d_out, int out_size, void* d_ws,
                              size_t ws_size, hipStream_t stream) {
  const float* vf  = (const float*)d_in[0];   // [N,128,3]
  const float* X   = (const float*)d_in[1];   // [N,128]
  const float* pos = (const float*)d_in[2];   // [N,3]
  const int* ei    = (const int*)d_in[3];     // [2,E]
  const float* W1  = (const float*)d_in[4];
  const float* b1  = (const float*)d_in[5];
  const float* W2  = (const float*)d_in[6];
  const float* b2  = (const float*)d_in[7];
  const float* Wr  = (const float*)d_in[8];
  const float* br  = (const float*)d_in[9];

  const int N = in_sizes[1] / D_DIM;
  const int E = in_sizes[3] / 2;
  const int* srcI = ei;
  const int* tgtI = ei + E;
  float* out = (float*)d_out;

  // workspace layout (16B-aligned chunks first)
  char* w = (char*)d_ws;
  EdgeRec* recs  = (EdgeRec*)w; w += (size_t)E * sizeof(EdgeRec);
  uint_t* merged = (uint_t*)w;  w += (size_t)N * 128 * 3 * sizeof(uint_t);
  int* counts    = (int*)w;     w += (size_t)N * sizeof(int);
  int* offsets   = (int*)w;     w += (size_t)(N + 1) * sizeof(int);
  int* cursor    = (int*)w;     w += (size_t)N * sizeof(int);
  int* chunks    = (int*)w;     w += 64 * sizeof(int);

  const int nch = (N + 1023) / 1024;  // 49 for N=50000 (<= 64 required)

  proj_kernel<<<(N + 63) / 64, 256, 0, stream>>>(X, W1, b1, W2, b2, vf, merged,
                                                 counts, N);
  hist_kernel<<<(E + 255) / 256, 256, 0, stream>>>(tgtI, counts, E);
  chunk_sum_kernel<<<nch, 256, 0, stream>>>(counts, chunks, N);
  scan_block_kernel<<<nch, 256, 0, stream>>>(counts, chunks, offsets, cursor,
                                             N, E);
  edge_geom_kernel<<<(E + 255) / 256, 256, 0, stream>>>(pos, srcI, tgtI, cursor,
                                                        recs, E);
  node_kernel<<<(N + NODES_PER_BLOCK - 1) / NODES_PER_BLOCK, 128, 0, stream>>>(
      merged, recs, offsets, Wr, br, out, N);
}